// Round 6
// baseline (7251.941 us; speedup 1.0000x reference)
//
#include <hip/hip_runtime.h>

#define SEQ   512
#define BATCH 64
#define D_IN  1024
#define D_LAT 1024
#define D_CAT 2048
#define NBLK  128      // j-blocks; each owns 8 output columns (j) x 4 gates = 32 W rows
#define JPB   8
#define ROWS  32
#define THREADS 512    // 8 waves: all own a 128-wide h-chunk; waves 4-7 also own a 256-wide x-chunk
#define GPS   67       // partial-gates batch stride: 67 = 3 dwords mod 32 -> <=3-way bank alias
#define POIS  0x7FC07FC0u   // (NaN,NaN) bf16 pair sentinel; real h pairs are always finite

typedef unsigned short u16;
typedef unsigned long long u64;
typedef __attribute__((ext_vector_type(8))) short short8;   // bf16x8 MFMA frag (4 VGPRs)
typedef __attribute__((ext_vector_type(4))) float floatx4;  // fp32x4 accumulator

__device__ __forceinline__ u16 f2bf(float f) {
    union { float f; unsigned u; } a; a.f = f;
    unsigned u = a.u;
    return (u16)((u + 0x7FFFu + ((u >> 16) & 1u)) >> 16);   // RNE
}

__device__ __forceinline__ float sigm(float x)  { return 1.0f / (1.0f + __expf(-x)); }
__device__ __forceinline__ float tanhf_(float x){ return 2.0f / (1.0f + __expf(-2.0f * x)) - 1.0f; }

__global__ void cvt_bf16(const float* __restrict__ x, u16* __restrict__ xb,
                         u16* __restrict__ hhist, int n8) {
    int i = blockIdx.x * blockDim.x + threadIdx.x;
    int stride = gridDim.x * blockDim.x;
    // poison slab 1 of hhist (slab 0 is real zeros; slabs >=2 poisoned in-loop)
    unsigned* p1 = (unsigned*)(hhist + (size_t)BATCH * D_LAT);
    for (int j = i; j < BATCH * D_LAT / 2; j += stride) p1[j] = POIS;
    for (; i < n8; i += stride) {
        float4 v0 = ((const float4*)x)[2 * i];
        float4 v1 = ((const float4*)x)[2 * i + 1];
        short8 o;
        o[0] = (short)f2bf(v0.x); o[1] = (short)f2bf(v0.y);
        o[2] = (short)f2bf(v0.z); o[3] = (short)f2bf(v0.w);
        o[4] = (short)f2bf(v1.x); o[5] = (short)f2bf(v1.y);
        o[6] = (short)f2bf(v1.z); o[7] = (short)f2bf(v1.w);
        *(short8*)(xb + 8 * (size_t)i) = o;
    }
}

// Dataflow protocol (NO tags, NO producer drain on the critical path):
//   - Slab s of hhist is pre-filled with POIS by the SAME thread that later
//     h-stores it, two steps earlier, with a vmcnt(0) drain BETWEEN poison(s)
//     and h-store(s-1). Therefore: any consumer that has verified slab s-1
//     from every producer is guaranteed poison(s) is at the coherence point
//     -> a consumer can never read pre-poison garbage.
//   - h-stores are agent-scope sc1 write-through u32 (full granule columns),
//     issued fire-and-forget. Consumers poll their exact input granules with
//     agent-scope u64 loads (bypass local L2 -- proven by rounds 0-4's
//     working remote-XCD polls) and accept once != POIS per u32 (4B
//     atomicity at the coherence point; a real pair never equals POIS).
//   - Slabs are never reused -> monotonic, no ABA, no reset race.

__launch_bounds__(THREADS, 2)
__global__ void lstm_persist(const float* __restrict__ Wf, const float* __restrict__ bfp,
                             const float* __restrict__ Wi, const float* __restrict__ bip,
                             const float* __restrict__ Wo, const float* __restrict__ bop,
                             const float* __restrict__ Wc, const float* __restrict__ bcp,
                             const u16* __restrict__ xb,     // [SEQ*BATCH*D_IN] bf16
                             u16* __restrict__ hhist,        // [(SEQ+1)*BATCH*D_LAT] bf16
                             float* __restrict__ out) {      // [SEQ*BATCH*D_LAT]
    __shared__ __align__(16) float gp[8][ROWS][GPS];         // 68608 B
    __shared__ float biasL[ROWS];

    const int tid  = threadIdx.x;
    const int jblk = blockIdx.x;
    const int c    = tid >> 6;          // wave id: h-chunk 0..7; waves 4-7 also x-chunk c-4
    const int lane = tid & 63;
    const int m    = lane & 15;         // W-row-in-tile (B n-index) == C col
    const int q    = lane >> 4;         // k-quad within k-step

    // ---- one-time: weight fragments -> registers ----
    short8 bregH[2][4];
    short8 bregX[2][8];
    #pragma unroll
    for (int rt = 0; rt < 2; ++rt) {
        const int rr  = rt * 16 + m;            // 0..31: gate g = rr>>3, j-in-block = rr&7
        const int g   = rr >> 3;
        const int jj2 = rr & 7;
        const float* Wg = (g == 0) ? Wf : (g == 1) ? Wi : (g == 2) ? Wo : Wc;
        const float* rowp = Wg + (size_t)(jblk * JPB + jj2) * D_CAT;
        #pragma unroll
        for (int ks = 0; ks < 4; ++ks) {
            const float* ph = rowp + c * 128 + ks * 32 + q * 8;          // h cols
            float4 h0 = *(const float4*)(ph);
            float4 h1 = *(const float4*)(ph + 4);
            short8 bh;
            bh[0] = (short)f2bf(h0.x); bh[1] = (short)f2bf(h0.y);
            bh[2] = (short)f2bf(h0.z); bh[3] = (short)f2bf(h0.w);
            bh[4] = (short)f2bf(h1.x); bh[5] = (short)f2bf(h1.y);
            bh[6] = (short)f2bf(h1.z); bh[7] = (short)f2bf(h1.w);
            bregH[rt][ks] = bh;
        }
        if (c >= 4) {
            #pragma unroll
            for (int ks = 0; ks < 8; ++ks) {
                const float* px = rowp + 1024 + (c - 4) * 256 + ks * 32 + q * 8;
                float4 x0 = *(const float4*)(px);
                float4 x1 = *(const float4*)(px + 4);
                short8 bx;
                bx[0] = (short)f2bf(x0.x); bx[1] = (short)f2bf(x0.y);
                bx[2] = (short)f2bf(x0.z); bx[3] = (short)f2bf(x0.w);
                bx[4] = (short)f2bf(x1.x); bx[5] = (short)f2bf(x1.y);
                bx[6] = (short)f2bf(x1.z); bx[7] = (short)f2bf(x1.w);
                bregX[rt][ks] = bx;
            }
        }
    }
    if (tid < ROWS) {
        const float* bsrc = (tid < 8) ? bfp : (tid < 16) ? bip : (tid < 24) ? bop : bcp;
        biasL[tid] = bsrc[jblk * JPB + (tid & 7)];
    }
    __syncthreads();

    // combine mapping: threads 0..255 -> (b = tid>>2, jpair a = tid&3)
    const int cb = tid >> 2;            // batch (valid for tid<256)
    const int ca = tid & 3;             // j pair -> jj = {2a, 2a+1}
    float creg0 = 0.0f, creg1 = 0.0f;   // c state, lives all 512 steps

    floatx4 acc[2][4];
    #pragma unroll
    for (int rt = 0; rt < 2; ++rt)
        #pragma unroll
        for (int bt = 0; bt < 4; ++bt)
            acc[rt][bt] = (floatx4){0.f, 0.f, 0.f, 0.f};

    // prologue: waves 4-7 compute x(0) contribution
    if (c >= 4) {
        const u16* xptr = xb + (size_t)(c - 4) * 256 + q * 8;
        #pragma unroll
        for (int ks = 0; ks < 8; ++ks)
            #pragma unroll
            for (int bt = 0; bt < 4; ++bt) {
                short8 a = *(const short8*)(xptr + (size_t)(bt * 16 + m) * 1024 + ks * 32);
                acc[0][bt] = __builtin_amdgcn_mfma_f32_16x16x32_bf16(a, bregX[0][ks], acc[0][bt], 0, 0, 0);
                acc[1][bt] = __builtin_amdgcn_mfma_f32_16x16x32_bf16(a, bregX[1][ks], acc[1][bt], 0, 0, 0);
            }
    }

    #pragma unroll 1
    for (int t = 0; t < SEQ; ++t) {
        // ===== h acquisition: issue all granule loads, then verify+retry =====
        const u16* hbase = hhist + (size_t)t * (BATCH * D_LAT) + c * 128 + q * 8;
        union Fr { u64 u[2]; short8 s; };
        Fr fr[4][4];
        #pragma unroll
        for (int ks = 0; ks < 4; ++ks)
            #pragma unroll
            for (int bt = 0; bt < 4; ++bt) {
                const u64* p = (const u64*)(hbase + (size_t)(bt * 16 + m) * 1024 + ks * 32);
                fr[ks][bt].u[0] = __hip_atomic_load(&p[0], __ATOMIC_RELAXED, __HIP_MEMORY_SCOPE_AGENT);
                fr[ks][bt].u[1] = __hip_atomic_load(&p[1], __ATOMIC_RELAXED, __HIP_MEMORY_SCOPE_AGENT);
            }
        #pragma unroll
        for (int ks = 0; ks < 4; ++ks)
            #pragma unroll
            for (int bt = 0; bt < 4; ++bt) {
                const u64* p = (const u64*)(hbase + (size_t)(bt * 16 + m) * 1024 + ks * 32);
                for (;;) {
                    u64 a0 = fr[ks][bt].u[0], a1 = fr[ks][bt].u[1];
                    int bad = ((unsigned)a0 == POIS) | ((unsigned)(a0 >> 32) == POIS)
                            | ((unsigned)a1 == POIS) | ((unsigned)(a1 >> 32) == POIS);
                    if (!__any(bad)) break;
                    __builtin_amdgcn_s_sleep(1);
                    fr[ks][bt].u[0] = __hip_atomic_load(&p[0], __ATOMIC_RELAXED, __HIP_MEMORY_SCOPE_AGENT);
                    fr[ks][bt].u[1] = __hip_atomic_load(&p[1], __ATOMIC_RELAXED, __HIP_MEMORY_SCOPE_AGENT);
                }
                acc[0][bt] = __builtin_amdgcn_mfma_f32_16x16x32_bf16(fr[ks][bt].s, bregH[0][ks], acc[0][bt], 0, 0, 0);
                acc[1][bt] = __builtin_amdgcn_mfma_f32_16x16x32_bf16(fr[ks][bt].s, bregH[1][ks], acc[1][bt], 0, 0, 0);
            }

        // C-layout: n(row-in-tile)=lane&15, m(batch-in-tile)=q*4+reg
        #pragma unroll
        for (int rt = 0; rt < 2; ++rt)
            #pragma unroll
            for (int bt = 0; bt < 4; ++bt)
                #pragma unroll
                for (int r = 0; r < 4; ++r)
                    gp[c][rt * 16 + m][bt * 16 + q * 4 + r] = acc[rt][bt][r];
        __syncthreads();   // S1: gp complete

        if (tid < 256) {
            const int jglob = jblk * JPB + 2 * ca;
            // poison slab t+2 FIRST (flight hidden under combine compute)
            if (t + 2 <= SEQ) {
                unsigned* pp = (unsigned*)(hhist + (size_t)(t + 2) * (BATCH * D_LAT)
                                                 + (size_t)cb * D_LAT + jglob);
                __hip_atomic_store(pp, POIS, __ATOMIC_RELAXED, __HIP_MEMORY_SCOPE_AGENT);
            }
            // ===== combine (waves 0-3) =====
            float h0, h1;
            {
                const int jj = 2 * ca;
                float pf = biasL[jj], pi = biasL[8 + jj], po = biasL[16 + jj], pg = biasL[24 + jj];
                #pragma unroll
                for (int cc = 0; cc < 8; ++cc) {
                    pf += gp[cc][jj][cb];
                    pi += gp[cc][8 + jj][cb];
                    po += gp[cc][16 + jj][cb];
                    pg += gp[cc][24 + jj][cb];
                }
                float ft = sigm(pf), it = sigm(pi), ot = sigm(po), gt = tanhf_(pg);
                creg0 = ft * creg0 + it * gt;
                h0 = ot * tanhf_(creg0);
            }
            {
                const int jj = 2 * ca + 1;
                float pf = biasL[jj], pi = biasL[8 + jj], po = biasL[16 + jj], pg = biasL[24 + jj];
                #pragma unroll
                for (int cc = 0; cc < 8; ++cc) {
                    pf += gp[cc][jj][cb];
                    pi += gp[cc][8 + jj][cb];
                    po += gp[cc][16 + jj][cb];
                    pg += gp[cc][24 + jj][cb];
                }
                float ft = sigm(pf), it = sigm(pi), ot = sigm(po), gt = tanhf_(pg);
                creg1 = ft * creg1 + it * gt;
                h1 = ot * tanhf_(creg1);
            }
            // drain: completes the poison(t+2) stores BEFORE h(t+1) is issued.
            // This is the linchpin of the no-garbage proof (see protocol note).
            asm volatile("s_waitcnt vmcnt(0)" ::: "memory");
            // packed sc1 write-through h store -- fire-and-forget, NO drain, NO tag
            unsigned hv = (unsigned)f2bf(h0) | ((unsigned)f2bf(h1) << 16);
            unsigned* hp = (unsigned*)(hhist + (size_t)(t + 1) * (BATCH * D_LAT)
                                             + (size_t)cb * D_LAT + jglob);
            __hip_atomic_store(hp, hv, __ATOMIC_RELAXED, __HIP_MEMORY_SCOPE_AGENT);
            // fp32 out store (8B, coalesced 32B per 4-lane group)
            float2 ov = make_float2(h0, h1);
            *(float2*)(out + (size_t)t * (BATCH * D_LAT) + (size_t)cb * D_LAT + jglob) = ov;
            // reset acc for next step's h accumulation
            #pragma unroll
            for (int rt = 0; rt < 2; ++rt)
                #pragma unroll
                for (int bt = 0; bt < 4; ++bt)
                    acc[rt][bt] = (floatx4){0.f, 0.f, 0.f, 0.f};
        } else {
            // ===== x(t+1) prefetch-GEMM (waves 4-7), overlapped with combine =====
            #pragma unroll
            for (int rt = 0; rt < 2; ++rt)
                #pragma unroll
                for (int bt = 0; bt < 4; ++bt)
                    acc[rt][bt] = (floatx4){0.f, 0.f, 0.f, 0.f};
            if (t + 1 < SEQ) {
                const u16* xptr = xb + (size_t)(t + 1) * (BATCH * D_IN) + (c - 4) * 256 + q * 8;
                #pragma unroll
                for (int ks = 0; ks < 8; ++ks)
                    #pragma unroll
                    for (int bt = 0; bt < 4; ++bt) {
                        short8 a = *(const short8*)(xptr + (size_t)(bt * 16 + m) * 1024 + ks * 32);
                        acc[0][bt] = __builtin_amdgcn_mfma_f32_16x16x32_bf16(a, bregX[0][ks], acc[0][bt], 0, 0, 0);
                        acc[1][bt] = __builtin_amdgcn_mfma_f32_16x16x32_bf16(a, bregX[1][ks], acc[1][bt], 0, 0, 0);
                    }
            }
        }

        __syncthreads();   // S2: protects gp across steps
    }
}

extern "C" void kernel_launch(void* const* d_in, const int* in_sizes, int n_in,
                              void* d_out, int out_size, void* d_ws, size_t ws_size,
                              hipStream_t stream) {
    const float* x  = (const float*)d_in[0];
    const float* Wf = (const float*)d_in[1];
    const float* bf = (const float*)d_in[2];
    const float* Wi = (const float*)d_in[3];
    const float* bi = (const float*)d_in[4];
    const float* Wo = (const float*)d_in[5];
    const float* bo = (const float*)d_in[6];
    const float* Wc = (const float*)d_in[7];
    const float* bc = (const float*)d_in[8];
    float* out = (float*)d_out;

    char* ws = (char*)d_ws;
    u16* hhist = (u16*)(ws + 1024);                                      // 513*64*1024*2 B
    u16* xb    = (u16*)(ws + 1024 + (size_t)(SEQ + 1) * BATCH * D_LAT * 2);

    // zero header + h_hist[0] (slab 0 = real zeros); slab 1 poisoned by cvt_bf16
    hipMemsetAsync(ws, 0, 1024 + (size_t)BATCH * D_LAT * 2, stream);
    cvt_bf16<<<2048, 256, 0, stream>>>(x, xb, hhist, SEQ * BATCH * D_IN / 8);
    lstm_persist<<<NBLK, THREADS, 0, stream>>>(Wf, bf, Wi, bi, Wo, bo, Wc, bc,
                                               xb, hhist, out);
}

// Round 7
// 4185.410 us; speedup vs baseline: 1.7327x; 1.7327x over previous
//
#include <hip/hip_runtime.h>

#define SEQ   512
#define BATCH 64
#define D_IN  1024
#define D_LAT 1024
#define D_CAT 2048
#define NBLK  128      // j-blocks; each owns 8 output columns (j) x 4 gates = 32 W rows
#define JPB   8
#define ROWS  32
#define THREADS 512    // 8 waves: all own a 128-wide h-chunk; waves 4-7 also own a 256-wide x-chunk
#define GPS   67       // partial-gates batch stride: 67 = 3 dwords mod 32 -> <=3-way bank alias

typedef unsigned short u16;
typedef __attribute__((ext_vector_type(8))) short short8;   // bf16x8 MFMA frag (4 VGPRs)
typedef __attribute__((ext_vector_type(4))) float floatx4;  // fp32x4 accumulator

__device__ __forceinline__ u16 f2bf(float f) {
    union { float f; unsigned u; } a; a.f = f;
    unsigned u = a.u;
    return (u16)((u + 0x7FFFu + ((u >> 16) & 1u)) >> 16);   // RNE
}

__device__ __forceinline__ float sigm(float x)  { return 1.0f / (1.0f + __expf(-x)); }
__device__ __forceinline__ float tanhf_(float x){ return 2.0f / (1.0f + __expf(-2.0f * x)) - 1.0f; }

__global__ void cvt_bf16(const float* __restrict__ x, u16* __restrict__ xb, int n8) {
    int i = blockIdx.x * blockDim.x + threadIdx.x;
    int stride = gridDim.x * blockDim.x;
    for (; i < n8; i += stride) {
        float4 v0 = ((const float4*)x)[2 * i];
        float4 v1 = ((const float4*)x)[2 * i + 1];
        short8 o;
        o[0] = (short)f2bf(v0.x); o[1] = (short)f2bf(v0.y);
        o[2] = (short)f2bf(v0.z); o[3] = (short)f2bf(v0.w);
        o[4] = (short)f2bf(v1.x); o[5] = (short)f2bf(v1.y);
        o[6] = (short)f2bf(v1.z); o[7] = (short)f2bf(v1.w);
        *(short8*)(xb + 8 * (size_t)i) = o;
    }
}

// h-history slab layout (BLOCK-MAJOR): slab s = hhist + s*BATCH*D_LAT, within
// a slab: [jblk][batch][8j] bf16. Producer block j's whole step output is ONE
// contiguous 1KB region written by 256 consecutive threads (4B each) as sc1
// write-through -- full-line coalesced bursts, so the vmcnt(0) drain before
// the tag waits on ~4 transactions per wave instead of 64 scattered islands.
// Readiness: slots[j] = t+1 published by the last combine wave (LDS wdone
// fetch_add picks it); each combine wave drains its OWN h-stores before its
// add, so all h bits are at the coherence point before the tag flips.
// Consumer wave c (h-cols [128c,128c+128)) needs producers 16c..16c+15:
// lane l polls slots[16c+(l&15)] (agent-scope, proven to observe remote-XCD
// stores); tags monotonic -> no reset race. h DATA loads are PLAIN vector
// loads (r6 lesson: agent-scope data loads are ~CP-latency each and
// serialize; plain loads on fresh addresses are safe and fast): sub-tile
// (ks,q) of wave c reads producer p = 16c+4ks+q at byte p*1024+(bt*16+m)*16.

__launch_bounds__(THREADS, 2)
__global__ void lstm_persist(const float* __restrict__ Wf, const float* __restrict__ bfp,
                             const float* __restrict__ Wi, const float* __restrict__ bip,
                             const float* __restrict__ Wo, const float* __restrict__ bop,
                             const float* __restrict__ Wc, const float* __restrict__ bcp,
                             const u16* __restrict__ xb,     // [SEQ*BATCH*D_IN] bf16
                             u16* __restrict__ hhist,        // [(SEQ+1)*BATCH*D_LAT] bf16 (block-major slabs)
                             float* __restrict__ out,        // [SEQ*BATCH*D_LAT]
                             unsigned* __restrict__ slots) { // [NBLK] readiness slots
    __shared__ __align__(16) float gp[8][ROWS][GPS];         // 68608 B
    __shared__ float biasL[ROWS];
    __shared__ unsigned wdone;                               // monotonic combine-wave arrivals

    const int tid  = threadIdx.x;
    const int jblk = blockIdx.x;
    const int c    = tid >> 6;          // wave id: h-chunk 0..7; waves 4-7 also x-chunk c-4
    const int lane = tid & 63;
    const int m    = lane & 15;         // W-row-in-tile (B n-index) == C col
    const int q    = lane >> 4;         // k-quad within k-step

    if (tid == 0) wdone = 0u;

    // ---- one-time: weight fragments -> registers ----
    // All waves: bregH = h-part cols [c*128, c*128+128)          (2 rt x 4 ks = 32 VGPR)
    // Waves 4-7: bregX = x-part cols [(c-4)*256, (c-4)*256+256)  (2 rt x 8 ks = 64 VGPR)
    short8 bregH[2][4];
    short8 bregX[2][8];
    #pragma unroll
    for (int rt = 0; rt < 2; ++rt) {
        const int rr  = rt * 16 + m;            // 0..31: gate g = rr>>3, j-in-block = rr&7
        const int g   = rr >> 3;
        const int jj2 = rr & 7;
        const float* Wg = (g == 0) ? Wf : (g == 1) ? Wi : (g == 2) ? Wo : Wc;
        const float* rowp = Wg + (size_t)(jblk * JPB + jj2) * D_CAT;
        #pragma unroll
        for (int ks = 0; ks < 4; ++ks) {
            const float* ph = rowp + c * 128 + ks * 32 + q * 8;          // h cols
            float4 h0 = *(const float4*)(ph);
            float4 h1 = *(const float4*)(ph + 4);
            short8 bh;
            bh[0] = (short)f2bf(h0.x); bh[1] = (short)f2bf(h0.y);
            bh[2] = (short)f2bf(h0.z); bh[3] = (short)f2bf(h0.w);
            bh[4] = (short)f2bf(h1.x); bh[5] = (short)f2bf(h1.y);
            bh[6] = (short)f2bf(h1.z); bh[7] = (short)f2bf(h1.w);
            bregH[rt][ks] = bh;
        }
        if (c >= 4) {
            #pragma unroll
            for (int ks = 0; ks < 8; ++ks) {
                const float* px = rowp + 1024 + (c - 4) * 256 + ks * 32 + q * 8;
                float4 x0 = *(const float4*)(px);
                float4 x1 = *(const float4*)(px + 4);
                short8 bx;
                bx[0] = (short)f2bf(x0.x); bx[1] = (short)f2bf(x0.y);
                bx[2] = (short)f2bf(x0.z); bx[3] = (short)f2bf(x0.w);
                bx[4] = (short)f2bf(x1.x); bx[5] = (short)f2bf(x1.y);
                bx[6] = (short)f2bf(x1.z); bx[7] = (short)f2bf(x1.w);
                bregX[rt][ks] = bx;
            }
        }
    }
    if (tid < ROWS) {
        const float* bsrc = (tid < 8) ? bfp : (tid < 16) ? bip : (tid < 24) ? bop : bcp;
        biasL[tid] = bsrc[jblk * JPB + (tid & 7)];
    }
    __syncthreads();

    // combine mapping: threads 0..255 -> (b = tid>>2, jpair a = tid&3)
    const int cb = tid >> 2;            // batch (valid for tid<256)
    const int ca = tid & 3;             // j pair -> jj = {2a, 2a+1}
    float creg0 = 0.0f, creg1 = 0.0f;   // c state, lives all 512 steps

    floatx4 acc[2][4];
    #pragma unroll
    for (int rt = 0; rt < 2; ++rt)
        #pragma unroll
        for (int bt = 0; bt < 4; ++bt)
            acc[rt][bt] = (floatx4){0.f, 0.f, 0.f, 0.f};

    // prologue: waves 4-7 compute x(0) contribution
    if (c >= 4) {
        const u16* xptr = xb + (size_t)(c - 4) * 256 + q * 8;
        #pragma unroll
        for (int ks = 0; ks < 8; ++ks)
            #pragma unroll
            for (int bt = 0; bt < 4; ++bt) {
                short8 a = *(const short8*)(xptr + (size_t)(bt * 16 + m) * 1024 + ks * 32);
                acc[0][bt] = __builtin_amdgcn_mfma_f32_16x16x32_bf16(a, bregX[0][ks], acc[0][bt], 0, 0, 0);
                acc[1][bt] = __builtin_amdgcn_mfma_f32_16x16x32_bf16(a, bregX[1][ks], acc[1][bt], 0, 0, 0);
            }
    }

    const unsigned* myslot = slots + 16 * c + (lane & 15);   // 4-lane redundant poll

    #pragma unroll 1
    for (int t = 0; t < SEQ; ++t) {
        // ===== per-wave wait: this wave's 16 h-producer blocks (16c..16c+15) =====
        for (;;) {
            unsigned v = __hip_atomic_load(myslot, __ATOMIC_RELAXED,
                                           __HIP_MEMORY_SCOPE_AGENT);
            if (__all((int)(v >= (unsigned)t))) break;
            __builtin_amdgcn_s_sleep(1);
        }
        asm volatile("" ::: "memory");   // keep h-loads below the readiness check

        // ===== h-chunk MFMA (critical path, all 8 waves) =====
        // Block-major slab: sub-tile (ks,q) comes from producer p = 16c+4ks+q.
        const u16* hslab = hhist + (size_t)t * (BATCH * D_LAT);
        #pragma unroll
        for (int ks = 0; ks < 4; ++ks) {
            const u16* hrow = hslab + (size_t)(16 * c + 4 * ks + q) * (BATCH * JPB);
            #pragma unroll
            for (int bt = 0; bt < 4; ++bt) {
                short8 a = *(const short8*)(hrow + (size_t)(bt * 16 + m) * JPB);
                acc[0][bt] = __builtin_amdgcn_mfma_f32_16x16x32_bf16(a, bregH[0][ks], acc[0][bt], 0, 0, 0);
                acc[1][bt] = __builtin_amdgcn_mfma_f32_16x16x32_bf16(a, bregH[1][ks], acc[1][bt], 0, 0, 0);
            }
        }

        // C-layout: n(row-in-tile)=lane&15, m(batch-in-tile)=q*4+reg
        #pragma unroll
        for (int rt = 0; rt < 2; ++rt)
            #pragma unroll
            for (int bt = 0; bt < 4; ++bt)
                #pragma unroll
                for (int r = 0; r < 4; ++r)
                    gp[c][rt * 16 + m][bt * 16 + q * 4 + r] = acc[rt][bt][r];
        __syncthreads();   // S1: gp complete

        if (tid < 256) {
            // ===== combine + h publish (waves 0-3) =====
            float h0, h1;
            {
                const int jj = 2 * ca;
                float pf = biasL[jj], pi = biasL[8 + jj], po = biasL[16 + jj], pg = biasL[24 + jj];
                #pragma unroll
                for (int cc = 0; cc < 8; ++cc) {
                    pf += gp[cc][jj][cb];
                    pi += gp[cc][8 + jj][cb];
                    po += gp[cc][16 + jj][cb];
                    pg += gp[cc][24 + jj][cb];
                }
                float ft = sigm(pf), it = sigm(pi), ot = sigm(po), gt = tanhf_(pg);
                creg0 = ft * creg0 + it * gt;
                h0 = ot * tanhf_(creg0);
            }
            {
                const int jj = 2 * ca + 1;
                float pf = biasL[jj], pi = biasL[8 + jj], po = biasL[16 + jj], pg = biasL[24 + jj];
                #pragma unroll
                for (int cc = 0; cc < 8; ++cc) {
                    pf += gp[cc][jj][cb];
                    pi += gp[cc][8 + jj][cb];
                    po += gp[cc][16 + jj][cb];
                    pg += gp[cc][24 + jj][cb];
                }
                float ft = sigm(pf), it = sigm(pi), ot = sigm(po), gt = tanhf_(pg);
                creg1 = ft * creg1 + it * gt;
                h1 = ot * tanhf_(creg1);
            }
            // packed sc1 write-through h store: block-major, tid-consecutive ->
            // one contiguous 1KB burst for the whole block.
            unsigned hv = (unsigned)f2bf(h0) | ((unsigned)f2bf(h1) << 16);
            unsigned* hp = (unsigned*)(hhist + (size_t)(t + 1) * (BATCH * D_LAT)
                                             + (size_t)jblk * (BATCH * JPB)
                                             + (size_t)cb * JPB + 2 * ca);
            __hip_atomic_store(hp, hv, __ATOMIC_RELAXED, __HIP_MEMORY_SCOPE_AGENT);

            // drain THIS wave's h-stores (ONLY the 4B h-store is pending), arrive.
            asm volatile("s_waitcnt vmcnt(0)" ::: "memory");
            if (lane == 0) {
                unsigned old = __hip_atomic_fetch_add(&wdone, 1u, __ATOMIC_RELAXED,
                                                      __HIP_MEMORY_SCOPE_WORKGROUP);
                if (old == 4u * (unsigned)t + 3u) {          // last combine wave of this block
                    __hip_atomic_store(&slots[jblk], (unsigned)(t + 1),
                                       __ATOMIC_RELAXED, __HIP_MEMORY_SCOPE_AGENT);
                }
            }

            // fp32 out store (8B) -- AFTER the publish, off the critical path
            float2 ov = make_float2(h0, h1);
            *(float2*)(out + (size_t)t * (BATCH * D_LAT) + (size_t)cb * D_LAT
                           + jblk * JPB + 2 * ca) = ov;

            // reset acc for next step's h accumulation
            #pragma unroll
            for (int rt = 0; rt < 2; ++rt)
                #pragma unroll
                for (int bt = 0; bt < 4; ++bt)
                    acc[rt][bt] = (floatx4){0.f, 0.f, 0.f, 0.f};
        } else {
            // ===== x(t+1) prefetch-GEMM (waves 4-7), overlapped with combine =====
            #pragma unroll
            for (int rt = 0; rt < 2; ++rt)
                #pragma unroll
                for (int bt = 0; bt < 4; ++bt)
                    acc[rt][bt] = (floatx4){0.f, 0.f, 0.f, 0.f};
            if (t + 1 < SEQ) {
                const u16* xptr = xb + (size_t)(t + 1) * (BATCH * D_IN) + (c - 4) * 256 + q * 8;
                #pragma unroll
                for (int ks = 0; ks < 8; ++ks)
                    #pragma unroll
                    for (int bt = 0; bt < 4; ++bt) {
                        short8 a = *(const short8*)(xptr + (size_t)(bt * 16 + m) * 1024 + ks * 32);
                        acc[0][bt] = __builtin_amdgcn_mfma_f32_16x16x32_bf16(a, bregX[0][ks], acc[0][bt], 0, 0, 0);
                        acc[1][bt] = __builtin_amdgcn_mfma_f32_16x16x32_bf16(a, bregX[1][ks], acc[1][bt], 0, 0, 0);
                    }
            }
        }

        __syncthreads();   // S2: protects gp across steps
    }
}

extern "C" void kernel_launch(void* const* d_in, const int* in_sizes, int n_in,
                              void* d_out, int out_size, void* d_ws, size_t ws_size,
                              hipStream_t stream) {
    const float* x  = (const float*)d_in[0];
    const float* Wf = (const float*)d_in[1];
    const float* bf = (const float*)d_in[2];
    const float* Wi = (const float*)d_in[3];
    const float* bi = (const float*)d_in[4];
    const float* Wo = (const float*)d_in[5];
    const float* bo = (const float*)d_in[6];
    const float* Wc = (const float*)d_in[7];
    const float* bc = (const float*)d_in[8];
    float* out = (float*)d_out;

    char* ws = (char*)d_ws;
    unsigned* slots = (unsigned*)ws;                                     // 128 u32 = 512 B
    u16* hhist = (u16*)(ws + 1024);                                      // 513*64*1024*2 B (block-major slabs)
    u16* xb    = (u16*)(ws + 1024 + (size_t)(SEQ + 1) * BATCH * D_LAT * 2);

    // zero slots + h_hist slab 0 (contiguous region) -- layout byte-identical
    // to the proven rounds 0-4 (no workspace growth).
    hipMemsetAsync(ws, 0, 1024 + (size_t)BATCH * D_LAT * 2, stream);
    cvt_bf16<<<2048, 256, 0, stream>>>(x, xb, SEQ * BATCH * D_IN / 8);
    lstm_persist<<<NBLK, THREADS, 0, stream>>>(Wf, bf, Wi, bi, Wo, bo, Wc, bc,
                                               xb, hhist, out, slots);
}